// Round 1
// baseline (359.273 us; speedup 1.0000x reference)
//
#include <hip/hip_runtime.h>
#include <hip/hip_bf16.h>
#include <cstdint>

typedef __attribute__((ext_vector_type(8))) short bf16x8;
typedef __attribute__((ext_vector_type(4))) float f32x4;

#define B_SZ 8192
#define NF 27
#define TROW 3456   // 27*128, per-sample stride of T buffer (bf16 elems)

__device__ __forceinline__ void gld_lds16(const void* g, void* l) {
    __builtin_amdgcn_global_load_lds(
        (const __attribute__((address_space(1))) unsigned int*)g,
        (__attribute__((address_space(3))) unsigned int*)l, 16, 0, 0);
}

// ---------------- convert fp32 (N x K) -> bf16 (N x Kp), zero-padded ----------------
__global__ void cvt_pad(const float* __restrict__ in, __hip_bfloat16* __restrict__ out,
                        int N, int K, int Kp) {
    int i = blockIdx.x * 256 + threadIdx.x;
    if (i >= N * Kp) return;
    int n = i / Kp, k = i - n * Kp;
    float v = (k < K) ? in[(size_t)n * K + k] : 0.f;
    out[i] = __float2bfloat16(v);
}

// ---------------- embedding gather-sum: T[b][1+t][:] = sum_p emb[t][idx][:] ----------------
__global__ __launch_bounds__(256) void emb_kernel(const int* __restrict__ idx,
                                                  const float* __restrict__ tab,
                                                  __hip_bfloat16* __restrict__ T) {
    int lane = threadIdx.x & 63, wv = threadIdx.x >> 6;
    int p = blockIdx.x * 4 + wv;          // p in [0, 26*8192)
    int t = p >> 13;                      // table
    int b = p & 8191;                     // sample
    const int* ip = idx + (size_t)t * 81920 + b * 10;
    const float* tb = tab + (size_t)t * 100000 * 128;
    float ax = 0.f, ay = 0.f;
    #pragma unroll
    for (int j = 0; j < 10; j++) {
        int r = ip[j];
        const float2* src = (const float2*)(tb + (size_t)r * 128) + lane;
        float2 v = *src;
        ax += v.x; ay += v.y;
    }
    __hip_bfloat162 o;
    o.x = __float2bfloat16(ax);
    o.y = __float2bfloat16(ay);
    ((__hip_bfloat162*)(T + (size_t)b * TROW + (1 + t) * 128))[lane] = o;
}

// ---------------- GEMM: C[m][n] = relu(sum_k A[m][k]*W[n][k] + bias[n]) ----------------
// A: M x K bf16, W: N x K bf16 (K multiple of 32), C: bf16 with row stride ldc.
// 128x128 tile, 4 waves (2x2), 16x16x32 MFMA, global_load_lds staging (m97 structure).
template<int RELU>
__global__ __launch_bounds__(256) void gemm_bt(const __hip_bfloat16* __restrict__ A,
                                               const __hip_bfloat16* __restrict__ W,
                                               const float* __restrict__ bias,
                                               __hip_bfloat16* __restrict__ C,
                                               int M, int N, int K, int ldc) {
    __shared__ __align__(16) __hip_bfloat16 As[128 * 32];
    __shared__ __align__(16) __hip_bfloat16 Bs[128 * 32];
    const int tid = threadIdx.x;
    const int lane = tid & 63, wave = tid >> 6;
    const int wm = wave >> 1, wn = wave & 1;
    const int m0 = blockIdx.y * 128, n0 = blockIdx.x * 128;

    // staging geometry: chunk c (0..7 over both A-halves): 1KB LDS each,
    // within a chunk: row = c*16 + lane/4, col(bf16) = (lane&3)*8
    const int r0 = (wave * 2 + 0) * 16 + (lane >> 2);
    const int r1 = (wave * 2 + 1) * 16 + (lane >> 2);
    const int cc = (lane & 3) * 8;
    const __hip_bfloat16* gA0 = A + (size_t)(m0 + r0) * K + cc;
    const __hip_bfloat16* gA1 = A + (size_t)(m0 + r1) * K + cc;
    const __hip_bfloat16* gB0 = W + (size_t)(n0 + r0) * K + cc;
    const __hip_bfloat16* gB1 = W + (size_t)(n0 + r1) * K + cc;
    __hip_bfloat16* lA0 = &As[(wave * 2 + 0) * 512];
    __hip_bfloat16* lA1 = &As[(wave * 2 + 1) * 512];
    __hip_bfloat16* lB0 = &Bs[(wave * 2 + 0) * 512];
    __hip_bfloat16* lB1 = &Bs[(wave * 2 + 1) * 512];

    f32x4 acc[4][4] = {};
    const int fr = lane & 15, fkb = (lane >> 4) * 8;

    for (int k0 = 0; k0 < K; k0 += 32) {
        __syncthreads();
        gld_lds16(gA0 + k0, lA0);
        gld_lds16(gA1 + k0, lA1);
        gld_lds16(gB0 + k0, lB0);
        gld_lds16(gB1 + k0, lB1);
        asm volatile("s_waitcnt vmcnt(0)" ::: "memory");
        __syncthreads();
        bf16x8 a[4], b[4];
        #pragma unroll
        for (int i = 0; i < 4; i++) {
            a[i] = *(const bf16x8*)&As[(wm * 64 + i * 16 + fr) * 32 + fkb];
            b[i] = *(const bf16x8*)&Bs[(wn * 64 + i * 16 + fr) * 32 + fkb];
        }
        #pragma unroll
        for (int i = 0; i < 4; i++)
            #pragma unroll
            for (int j = 0; j < 4; j++)
                acc[i][j] = __builtin_amdgcn_mfma_f32_16x16x32_bf16(a[i], b[j], acc[i][j], 0, 0, 0);
    }

    const int fq = lane >> 4;
    #pragma unroll
    for (int i = 0; i < 4; i++) {
        #pragma unroll
        for (int j = 0; j < 4; j++) {
            int n = n0 + wn * 64 + j * 16 + fr;
            float bv = bias[n];
            #pragma unroll
            for (int r = 0; r < 4; r++) {
                int m = m0 + wm * 64 + i * 16 + fq * 4 + r;
                float v = acc[i][j][r] + bv;
                if (RELU) v = fmaxf(v, 0.f);
                C[(size_t)m * ldc + n] = __float2bfloat16(v);
            }
        }
    }
}

// ---------------- interaction: per sample, 32x32 Gram of T (rows 27..31 zero) ----------------
// z[b][0:128] = x (T row 0), z[b][128+p] = Z[m][n] for m<n<27 (triu order), z[b][479:512]=0
__global__ __launch_bounds__(64) void interact_kernel(const __hip_bfloat16* __restrict__ T,
                                                      __hip_bfloat16* __restrict__ z) {
    __shared__ __align__(16) __hip_bfloat16 S[32 * 128];
    int b = blockIdx.x;
    int lane = threadIdx.x;
    const uint4* src = (const uint4*)(T + (size_t)b * TROW);
    uint4* dst = (uint4*)S;
    for (int i = lane; i < 432; i += 64) dst[i] = src[i];   // 27*128 bf16 = 432 x 16B
    uint4 z4 = {0u, 0u, 0u, 0u};
    for (int i = 432 + lane; i < 512; i += 64) dst[i] = z4; // zero rows 27..31
    __syncthreads();

    const int fr = lane & 15, fkb = (lane >> 4) * 8;
    bf16x8 fr2[2][4];
    #pragma unroll
    for (int mi = 0; mi < 2; mi++)
        #pragma unroll
        for (int kt = 0; kt < 4; kt++)
            fr2[mi][kt] = *(const bf16x8*)&S[(mi * 16 + fr) * 128 + kt * 32 + fkb];

    f32x4 acc[2][2] = {};
    #pragma unroll
    for (int kt = 0; kt < 4; kt++)
        #pragma unroll
        for (int mi = 0; mi < 2; mi++)
            #pragma unroll
            for (int ni = 0; ni < 2; ni++)
                acc[mi][ni] = __builtin_amdgcn_mfma_f32_16x16x32_bf16(fr2[mi][kt], fr2[ni][kt], acc[mi][ni], 0, 0, 0);

    __hip_bfloat16* zb = z + (size_t)b * 512;
    // copy x
    zb[lane] = S[lane];
    zb[64 + lane] = S[64 + lane];
    // zero pad cols 479..511
    if (lane < 33) zb[479 + lane] = __float2bfloat16(0.f);
    // upper triangle scatter
    const int fq = lane >> 4;
    #pragma unroll
    for (int mi = 0; mi < 2; mi++) {
        #pragma unroll
        for (int ni = 0; ni < 2; ni++) {
            #pragma unroll
            for (int r = 0; r < 4; r++) {
                int m = mi * 16 + fq * 4 + r;
                int n = ni * 16 + fr;
                if (m < 27 && n < 27 && m < n) {
                    int p = m * 26 - (m * (m - 1)) / 2 + (n - m - 1);
                    zb[128 + p] = __float2bfloat16(acc[mi][ni][r]);
                }
            }
        }
    }
}

// ---------------- final layer: dot(h[256], w) + b -> sigmoid ----------------
__global__ __launch_bounds__(256) void final_kernel(const __hip_bfloat16* __restrict__ h,
                                                    const float* __restrict__ w,
                                                    const float* __restrict__ bias,
                                                    float* __restrict__ out) {
    int lane = threadIdx.x & 63, wv = threadIdx.x >> 6;
    int s = blockIdx.x * 4 + wv;
    const __hip_bfloat16* hp = h + (size_t)s * 256;
    float sum = 0.f;
    #pragma unroll
    for (int i = 0; i < 4; i++) {
        int k = i * 64 + lane;
        sum += __bfloat162float(hp[k]) * w[k];
    }
    #pragma unroll
    for (int off = 32; off; off >>= 1) sum += __shfl_down(sum, off, 64);
    if (lane == 0) out[s] = 1.f / (1.f + expf(-(sum + bias[0])));
}

extern "C" void kernel_launch(void* const* d_in, const int* in_sizes, int n_in,
                              void* d_out, int out_size, void* d_ws, size_t ws_size,
                              hipStream_t stream) {
    const float* dense_x = (const float*)d_in[0];
    const int* sidx      = (const int*)d_in[1];
    const float* emb     = (const float*)d_in[2];
    const float* bw0 = (const float*)d_in[3];  const float* bb0 = (const float*)d_in[4];
    const float* bw1 = (const float*)d_in[5];  const float* bb1 = (const float*)d_in[6];
    const float* bw2 = (const float*)d_in[7];  const float* bb2 = (const float*)d_in[8];
    const float* tw0 = (const float*)d_in[9];  const float* tb0 = (const float*)d_in[10];
    const float* tw1 = (const float*)d_in[11]; const float* tb1 = (const float*)d_in[12];
    const float* tw2 = (const float*)d_in[13]; const float* tb2 = (const float*)d_in[14];
    const float* tw3 = (const float*)d_in[15]; const float* tb3 = (const float*)d_in[16];
    const float* tw4 = (const float*)d_in[17]; const float* tb4 = (const float*)d_in[18];
    float* out = (float*)d_out;

    char* ws = (char*)d_ws;
    size_t off = 0;
    auto alloc = [&](size_t bytes) {
        off = (off + 255) & ~(size_t)255;
        void* p = ws + off;
        off += bytes;
        return p;
    };
    __hip_bfloat16* A0  = (__hip_bfloat16*)alloc((size_t)B_SZ * 32 * 2);
    __hip_bfloat16* Wb0 = (__hip_bfloat16*)alloc((size_t)512 * 32 * 2);
    __hip_bfloat16* Wb1 = (__hip_bfloat16*)alloc((size_t)256 * 512 * 2);
    __hip_bfloat16* Wb2 = (__hip_bfloat16*)alloc((size_t)128 * 256 * 2);
    __hip_bfloat16* Wt0 = (__hip_bfloat16*)alloc((size_t)1024 * 512 * 2);
    __hip_bfloat16* Wt1 = (__hip_bfloat16*)alloc((size_t)1024 * 1024 * 2);
    __hip_bfloat16* Wt2 = (__hip_bfloat16*)alloc((size_t)512 * 1024 * 2);
    __hip_bfloat16* Wt3 = (__hip_bfloat16*)alloc((size_t)256 * 512 * 2);
    __hip_bfloat16* bufA = (__hip_bfloat16*)alloc((size_t)B_SZ * 1024 * 2);
    __hip_bfloat16* bufB = (__hip_bfloat16*)alloc((size_t)B_SZ * 1024 * 2);
    __hip_bfloat16* Tbuf = (__hip_bfloat16*)alloc((size_t)B_SZ * TROW * 2);
    __hip_bfloat16* zbuf = (__hip_bfloat16*)alloc((size_t)B_SZ * 512 * 2);

    auto cvt = [&](const float* in, __hip_bfloat16* o, int N, int K, int Kp) {
        int total = N * Kp;
        cvt_pad<<<(total + 255) / 256, 256, 0, stream>>>(in, o, N, K, Kp);
    };
    cvt(dense_x, A0, B_SZ, 13, 32);
    cvt(bw0, Wb0, 512, 13, 32);
    cvt(bw1, Wb1, 256, 512, 512);
    cvt(bw2, Wb2, 128, 256, 256);
    cvt(tw0, Wt0, 1024, 479, 512);
    cvt(tw1, Wt1, 1024, 1024, 1024);
    cvt(tw2, Wt2, 512, 1024, 1024);
    cvt(tw3, Wt3, 256, 512, 512);

    // bottom MLP
    gemm_bt<1><<<dim3(512 / 128, B_SZ / 128), 256, 0, stream>>>(A0, Wb0, bb0, bufA, B_SZ, 512, 32, 512);
    gemm_bt<1><<<dim3(256 / 128, B_SZ / 128), 256, 0, stream>>>(bufA, Wb1, bb1, bufB, B_SZ, 256, 512, 256);
    gemm_bt<1><<<dim3(128 / 128, B_SZ / 128), 256, 0, stream>>>(bufB, Wb2, bb2, Tbuf, B_SZ, 128, 256, TROW);

    // embeddings into T rows 1..26
    emb_kernel<<<26 * B_SZ / 4, 256, 0, stream>>>(sidx, emb, Tbuf);

    // interaction -> z (B x 512, padded)
    interact_kernel<<<B_SZ, 64, 0, stream>>>(Tbuf, zbuf);

    // top MLP
    gemm_bt<1><<<dim3(1024 / 128, B_SZ / 128), 256, 0, stream>>>(zbuf, Wt0, tb0, bufA, B_SZ, 1024, 512, 1024);
    gemm_bt<1><<<dim3(1024 / 128, B_SZ / 128), 256, 0, stream>>>(bufA, Wt1, tb1, bufB, B_SZ, 1024, 1024, 1024);
    gemm_bt<1><<<dim3(512 / 128, B_SZ / 128), 256, 0, stream>>>(bufB, Wt2, tb2, bufA, B_SZ, 512, 1024, 512);
    gemm_bt<1><<<dim3(256 / 128, B_SZ / 128), 256, 0, stream>>>(bufA, Wt3, tb3, bufB, B_SZ, 256, 512, 256);

    // final dot + sigmoid
    final_kernel<<<B_SZ / 4, 256, 0, stream>>>(bufB, tw4, tb4, out);
}

// Round 2
// 337.407 us; speedup vs baseline: 1.0648x; 1.0648x over previous
//
#include <hip/hip_runtime.h>
#include <hip/hip_bf16.h>
#include <cstdint>

typedef __attribute__((ext_vector_type(8))) short bf16x8;
typedef __attribute__((ext_vector_type(4))) float f32x4;

#define B_SZ 8192
#define NF 27
#define TROW 3456   // 27*128, per-sample stride of T buffer (bf16 elems)

__device__ __forceinline__ void gld_lds16(const void* g, void* l) {
    __builtin_amdgcn_global_load_lds(
        (const __attribute__((address_space(1))) unsigned int*)g,
        (__attribute__((address_space(3))) unsigned int*)l, 16, 0, 0);
}

// ---------------- batched convert fp32 (N x K) -> bf16 (N x Kp), zero-padded ----------------
struct CvtJob { const float* in; __hip_bfloat16* out; int N, K, Kp; };
struct CvtJobs { CvtJob j[8]; int start[9]; };

__global__ __launch_bounds__(256) void cvt_all(CvtJobs jobs) {
    int gid = blockIdx.x * 256 + threadIdx.x;
    if (gid >= jobs.start[8]) return;
    int k = 0;
    #pragma unroll
    for (int i = 1; i < 8; i++) if (gid >= jobs.start[i]) k = i;
    const CvtJob& J = jobs.j[k];
    int local = gid - jobs.start[k];
    int n = local / J.Kp, kk = local - n * J.Kp;
    float v = (kk < J.K) ? J.in[(size_t)n * J.K + kk] : 0.f;
    J.out[local] = __float2bfloat16(v);
}

// ---------------- embedding gather-sum: T[b][1+t][:] = sum_p emb[t][idx][:] ----------------
__global__ __launch_bounds__(256) void emb_kernel(const int* __restrict__ idx,
                                                  const float* __restrict__ tab,
                                                  __hip_bfloat16* __restrict__ T) {
    int lane = threadIdx.x & 63, wv = threadIdx.x >> 6;
    int p = blockIdx.x * 4 + wv;          // p in [0, 26*8192)
    int t = p >> 13;                      // table
    int b = p & 8191;                     // sample
    const int* ip = idx + (size_t)t * 81920 + b * 10;
    const float* tb = tab + (size_t)t * 100000 * 128;
    float ax = 0.f, ay = 0.f;
    #pragma unroll
    for (int j = 0; j < 10; j++) {
        int r = ip[j];
        const float2* src = (const float2*)(tb + (size_t)r * 128) + lane;
        float2 v = *src;
        ax += v.x; ay += v.y;
    }
    __hip_bfloat162 o;
    o.x = __float2bfloat16(ax);
    o.y = __float2bfloat16(ay);
    ((__hip_bfloat162*)(T + (size_t)b * TROW + (1 + t) * 128))[lane] = o;
}

// ---------------- GEMM: C[m][n] = relu(sum_k A[m][k]*W[n][k] + bias[n]) ----------------
// A: M x K bf16, W: N x K bf16 (K mult of 32), C: bf16 row stride ldc.
// TM x TN tile, 4 waves in WM x WN grid, 16x16x32 MFMA, global_load_lds staging.
template<int TM, int TN, int WM, int WN, int RELU>
__global__ __launch_bounds__(256) void gemm_t(const __hip_bfloat16* __restrict__ A,
                                              const __hip_bfloat16* __restrict__ W,
                                              const float* __restrict__ bias,
                                              __hip_bfloat16* __restrict__ C,
                                              int M, int N, int K, int ldc) {
    constexpr int ROWS = TM + TN;
    constexpr int CH = ROWS * 4 / 256;        // 16B chunks per thread
    constexpr int MI = TM / WM / 16;
    constexpr int NI = TN / WN / 16;
    __shared__ __align__(16) __hip_bfloat16 ABs[ROWS * 32];

    const int tid = threadIdx.x;
    const int lane = tid & 63, wave = tid >> 6;
    const int wmI = wave / WN, wnI = wave % WN;
    const int m0 = blockIdx.y * TM, n0 = blockIdx.x * TN;

    // staging: chunk gid = c*256+tid -> row = gid>>2, col = (gid&3)*8 (bf16)
    const __hip_bfloat16* gp[CH];
    #pragma unroll
    for (int c = 0; c < CH; c++) {
        int gid = c * 256 + tid;
        int row = gid >> 2, col = (gid & 3) * 8;
        gp[c] = (row < TM ? A + (size_t)(m0 + row) * K
                          : W + (size_t)(n0 + row - TM) * K) + col;
    }

    f32x4 acc[MI][NI] = {};
    const int fr = lane & 15, fkb = (lane >> 4) * 8;

    for (int k0 = 0; k0 < K; k0 += 32) {
        __syncthreads();
        #pragma unroll
        for (int c = 0; c < CH; c++)
            gld_lds16(gp[c] + k0, &ABs[(c * 256 + wave * 64) * 8]);
        asm volatile("s_waitcnt vmcnt(0)" ::: "memory");
        __syncthreads();
        bf16x8 a[MI], b[NI];
        #pragma unroll
        for (int i = 0; i < MI; i++)
            a[i] = *(const bf16x8*)&ABs[(wmI * (TM / WM) + i * 16 + fr) * 32 + fkb];
        #pragma unroll
        for (int j = 0; j < NI; j++)
            b[j] = *(const bf16x8*)&ABs[(TM + wnI * (TN / WN) + j * 16 + fr) * 32 + fkb];
        #pragma unroll
        for (int i = 0; i < MI; i++)
            #pragma unroll
            for (int j = 0; j < NI; j++)
                acc[i][j] = __builtin_amdgcn_mfma_f32_16x16x32_bf16(a[i], b[j], acc[i][j], 0, 0, 0);
    }

    const int fq = lane >> 4;
    #pragma unroll
    for (int i = 0; i < MI; i++) {
        #pragma unroll
        for (int j = 0; j < NI; j++) {
            int n = n0 + wnI * (TN / WN) + j * 16 + fr;
            float bv = bias[n];
            #pragma unroll
            for (int r = 0; r < 4; r++) {
                int m = m0 + wmI * (TM / WM) + i * 16 + fq * 4 + r;
                float v = acc[i][j][r] + bv;
                if (RELU) v = fmaxf(v, 0.f);
                C[(size_t)m * ldc + n] = __float2bfloat16(v);
            }
        }
    }
}

// ---------------- interaction: 4 samples/block, 32x32 Gram of T (rows 27..31 zero) ----------------
__global__ __launch_bounds__(256) void interact_kernel(const __hip_bfloat16* __restrict__ T,
                                                       __hip_bfloat16* __restrict__ z) {
    __shared__ __align__(16) __hip_bfloat16 S[4][32 * 128];
    int lane = threadIdx.x & 63, wave = threadIdx.x >> 6;
    int b = blockIdx.x * 4 + wave;
    __hip_bfloat16* Sw = S[wave];
    const uint4* src = (const uint4*)(T + (size_t)b * TROW);
    uint4* dst = (uint4*)Sw;
    for (int i = lane; i < 432; i += 64) dst[i] = src[i];   // 27*128 bf16 = 432 x 16B
    uint4 z4 = {0u, 0u, 0u, 0u};
    for (int i = 432 + lane; i < 512; i += 64) dst[i] = z4; // zero rows 27..31
    __syncthreads();

    const int fr = lane & 15, fkb = (lane >> 4) * 8;
    bf16x8 fr2[2][4];
    #pragma unroll
    for (int mi = 0; mi < 2; mi++)
        #pragma unroll
        for (int kt = 0; kt < 4; kt++)
            fr2[mi][kt] = *(const bf16x8*)&Sw[(mi * 16 + fr) * 128 + kt * 32 + fkb];

    f32x4 acc[2][2] = {};
    #pragma unroll
    for (int kt = 0; kt < 4; kt++)
        #pragma unroll
        for (int mi = 0; mi < 2; mi++)
            #pragma unroll
            for (int ni = 0; ni < 2; ni++)
                acc[mi][ni] = __builtin_amdgcn_mfma_f32_16x16x32_bf16(fr2[mi][kt], fr2[ni][kt], acc[mi][ni], 0, 0, 0);

    __hip_bfloat16* zb = z + (size_t)b * 512;
    zb[lane] = Sw[lane];
    zb[64 + lane] = Sw[64 + lane];
    if (lane < 33) zb[479 + lane] = __float2bfloat16(0.f);
    const int fq = lane >> 4;
    #pragma unroll
    for (int mi = 0; mi < 2; mi++) {
        #pragma unroll
        for (int ni = 0; ni < 2; ni++) {
            #pragma unroll
            for (int r = 0; r < 4; r++) {
                int m = mi * 16 + fq * 4 + r;
                int n = ni * 16 + fr;
                if (m < 27 && n < 27 && m < n) {
                    int p = m * 26 - (m * (m - 1)) / 2 + (n - m - 1);
                    zb[128 + p] = __float2bfloat16(acc[mi][ni][r]);
                }
            }
        }
    }
}

// ---------------- final layer: dot(h[256], w) + b -> sigmoid ----------------
__global__ __launch_bounds__(256) void final_kernel(const __hip_bfloat16* __restrict__ h,
                                                    const float* __restrict__ w,
                                                    const float* __restrict__ bias,
                                                    float* __restrict__ out) {
    int lane = threadIdx.x & 63, wv = threadIdx.x >> 6;
    int s = blockIdx.x * 4 + wv;
    const __hip_bfloat16* hp = h + (size_t)s * 256;
    float sum = 0.f;
    #pragma unroll
    for (int i = 0; i < 4; i++) {
        int k = i * 64 + lane;
        sum += __bfloat162float(hp[k]) * w[k];
    }
    #pragma unroll
    for (int off = 32; off; off >>= 1) sum += __shfl_down(sum, off, 64);
    if (lane == 0) out[s] = 1.f / (1.f + expf(-(sum + bias[0])));
}

extern "C" void kernel_launch(void* const* d_in, const int* in_sizes, int n_in,
                              void* d_out, int out_size, void* d_ws, size_t ws_size,
                              hipStream_t stream) {
    const float* dense_x = (const float*)d_in[0];
    const int* sidx      = (const int*)d_in[1];
    const float* emb     = (const float*)d_in[2];
    const float* bw0 = (const float*)d_in[3];  const float* bb0 = (const float*)d_in[4];
    const float* bw1 = (const float*)d_in[5];  const float* bb1 = (const float*)d_in[6];
    const float* bw2 = (const float*)d_in[7];  const float* bb2 = (const float*)d_in[8];
    const float* tw0 = (const float*)d_in[9];  const float* tb0 = (const float*)d_in[10];
    const float* tw1 = (const float*)d_in[11]; const float* tb1 = (const float*)d_in[12];
    const float* tw2 = (const float*)d_in[13]; const float* tb2 = (const float*)d_in[14];
    const float* tw3 = (const float*)d_in[15]; const float* tb3 = (const float*)d_in[16];
    const float* tw4 = (const float*)d_in[17]; const float* tb4 = (const float*)d_in[18];
    float* out = (float*)d_out;

    char* ws = (char*)d_ws;
    size_t off = 0;
    auto alloc = [&](size_t bytes) {
        off = (off + 255) & ~(size_t)255;
        void* p = ws + off;
        off += bytes;
        return p;
    };
    __hip_bfloat16* A0  = (__hip_bfloat16*)alloc((size_t)B_SZ * 32 * 2);
    __hip_bfloat16* Wb0 = (__hip_bfloat16*)alloc((size_t)512 * 32 * 2);
    __hip_bfloat16* Wb1 = (__hip_bfloat16*)alloc((size_t)256 * 512 * 2);
    __hip_bfloat16* Wb2 = (__hip_bfloat16*)alloc((size_t)128 * 256 * 2);
    __hip_bfloat16* Wt0 = (__hip_bfloat16*)alloc((size_t)1024 * 512 * 2);
    __hip_bfloat16* Wt1 = (__hip_bfloat16*)alloc((size_t)1024 * 1024 * 2);
    __hip_bfloat16* Wt2 = (__hip_bfloat16*)alloc((size_t)512 * 1024 * 2);
    __hip_bfloat16* Wt3 = (__hip_bfloat16*)alloc((size_t)256 * 512 * 2);
    __hip_bfloat16* bufA = (__hip_bfloat16*)alloc((size_t)B_SZ * 1024 * 2);
    __hip_bfloat16* bufB = (__hip_bfloat16*)alloc((size_t)B_SZ * 1024 * 2);
    __hip_bfloat16* Tbuf = (__hip_bfloat16*)alloc((size_t)B_SZ * TROW * 2);
    __hip_bfloat16* zbuf = (__hip_bfloat16*)alloc((size_t)B_SZ * 512 * 2);

    // single batched conversion launch
    CvtJobs cj;
    auto setJob = [&](int i, const float* in, __hip_bfloat16* o, int N, int K, int Kp) {
        cj.j[i] = {in, o, N, K, Kp};
    };
    setJob(0, dense_x, A0, B_SZ, 13, 32);
    setJob(1, bw0, Wb0, 512, 13, 32);
    setJob(2, bw1, Wb1, 256, 512, 512);
    setJob(3, bw2, Wb2, 128, 256, 256);
    setJob(4, tw0, Wt0, 1024, 479, 512);
    setJob(5, tw1, Wt1, 1024, 1024, 1024);
    setJob(6, tw2, Wt2, 512, 1024, 1024);
    setJob(7, tw3, Wt3, 256, 512, 512);
    cj.start[0] = 0;
    for (int i = 0; i < 8; i++) cj.start[i + 1] = cj.start[i] + cj.j[i].N * cj.j[i].Kp;
    int totalCvt = cj.start[8];
    cvt_all<<<(totalCvt + 255) / 256, 256, 0, stream>>>(cj);

    // bottom MLP
    gemm_t<128,128,2,2,1><<<dim3(512/128, B_SZ/128), 256, 0, stream>>>(A0, Wb0, bb0, bufA, B_SZ, 512, 32, 512);
    gemm_t<128, 64,2,2,1><<<dim3(256/ 64, B_SZ/128), 256, 0, stream>>>(bufA, Wb1, bb1, bufB, B_SZ, 256, 512, 256);
    gemm_t< 64, 64,2,2,1><<<dim3(128/ 64, B_SZ/ 64), 256, 0, stream>>>(bufB, Wb2, bb2, Tbuf, B_SZ, 128, 256, TROW);

    // embeddings into T rows 1..26
    emb_kernel<<<26 * B_SZ / 4, 256, 0, stream>>>(sidx, emb, Tbuf);

    // interaction -> z (B x 512, padded)
    interact_kernel<<<B_SZ / 4, 256, 0, stream>>>(Tbuf, zbuf);

    // top MLP
    gemm_t<128,128,2,2,1><<<dim3(1024/128, B_SZ/128), 256, 0, stream>>>(zbuf, Wt0, tb0, bufA, B_SZ, 1024, 512, 1024);
    gemm_t<128,128,2,2,1><<<dim3(1024/128, B_SZ/128), 256, 0, stream>>>(bufA, Wt1, tb1, bufB, B_SZ, 1024, 1024, 1024);
    gemm_t<128, 64,2,2,1><<<dim3( 512/ 64, B_SZ/128), 256, 0, stream>>>(bufB, Wt2, tb2, bufA, B_SZ, 512, 1024, 512);
    gemm_t<128, 64,2,2,1><<<dim3( 256/ 64, B_SZ/128), 256, 0, stream>>>(bufA, Wt3, tb3, bufB, B_SZ, 256, 512, 256);

    // final dot + sigmoid
    final_kernel<<<B_SZ / 4, 256, 0, stream>>>(bufB, tw4, tb4, out);
}